// Round 11
// baseline (456.585 us; speedup 1.0000x reference)
//
#include <hip/hip_runtime.h>
#include <cstdint>
#include <cstddef>

#define NN   20000
#define NPAD 20224   // 158*128, 316*64
#define EE   640000
#define E2   660000   // EE + NN self loops
#define HHD  4
#define CC   64
#define HC   256
#define NEG  0.2f

typedef short bf16x8 __attribute__((ext_vector_type(8)));
typedef float f32x4 __attribute__((ext_vector_type(4)));

__device__ __forceinline__ float sigmoidf_(float x) { return 1.0f / (1.0f + __expf(-x)); }

__device__ __forceinline__ float wred_sum(float v) {
#pragma unroll
    for (int d = 32; d; d >>= 1) v += __shfl_xor(v, d, 64);
    return v;
}

__device__ __forceinline__ unsigned short f2bf(float f) {
    unsigned u = __float_as_uint(f);
    u = (u + 0x7fff + ((u >> 16) & 1)) >> 16;   // RNE
    return (unsigned short)u;
}
__device__ __forceinline__ float bfval(unsigned short h) { return __uint_as_float(((unsigned)h) << 16); }
__device__ __forceinline__ float bf_lo(unsigned u) { return __uint_as_float(u << 16); }
__device__ __forceinline__ float bf_hi(unsigned u) { return __uint_as_float(u & 0xffff0000u); }

// ---------------- CSR build ----------------
__global__ void count_edges(const int* __restrict__ ei, int* __restrict__ cnt) {
    int e = blockIdx.x * 256 + threadIdx.x;
    if (e < E2) {
        int d = (e < EE) ? ei[EE + e] : (e - EE);
        atomicAdd(&cnt[d], 1);
    }
}

__global__ __launch_bounds__(1024) void scan_off(const int* __restrict__ cnt,
                                                 int* __restrict__ off,
                                                 int* __restrict__ cur) {
    __shared__ int buf[1024];
    int t = threadIdx.x;
    int base = t * 20;
    int local[20];
    int s = 0;
#pragma unroll
    for (int i = 0; i < 20; i++) {
        int idx = base + i;
        int v = (idx < NN) ? cnt[idx] : 0;
        local[i] = v;
        s += v;
    }
    buf[t] = s;
    __syncthreads();
    for (int d = 1; d < 1024; d <<= 1) {
        int tv = (t >= d) ? buf[t - d] : 0;
        __syncthreads();
        buf[t] += tv;
        __syncthreads();
    }
    int run = buf[t] - s;
#pragma unroll
    for (int i = 0; i < 20; i++) {
        int idx = base + i;
        if (idx < NN) { off[idx] = run; cur[idx] = run; }
        run += local[i];
    }
    if (t == 1023) off[NN] = buf[1023];
}

__global__ void scatter_edges(const int* __restrict__ ei, int* __restrict__ cur,
                              int* __restrict__ csr) {
    int e = blockIdx.x * 256 + threadIdx.x;
    if (e < E2) {
        int s, d;
        if (e < EE) { s = ei[e]; d = ei[EE + e]; }
        else        { s = e - EE; d = s; }
        int p = atomicAdd(&cur[d], 1);
        csr[p] = s;
    }
}

// ---------------- fused prep: weight repack (hi/lo W^T) + x split + bcat ----------------
#define WTOT 212992
__global__ void prep_inputs(const float* __restrict__ x,
                            const float* __restrict__ w_in, const float* __restrict__ lin_w0,
                            const float* __restrict__ lin_w12,
                            const float* __restrict__ nc1, const float* __restrict__ oc1,
                            const float* __restrict__ ec1,
                            const float* __restrict__ nb, const float* __restrict__ ob,
                            const float* __restrict__ eb,
                            unsigned short* __restrict__ whi, unsigned short* __restrict__ wlo,
                            float* __restrict__ bcat,
                            unsigned short* __restrict__ xh, unsigned short* __restrict__ xl) {
    int idx = blockIdx.x * 256 + threadIdx.x;
    if (idx < NN * 64) {
        float4 v = ((const float4*)x)[idx];
        ushort4 hi, lo;
        hi.x = f2bf(v.x); lo.x = f2bf(v.x - bfval(hi.x));
        hi.y = f2bf(v.y); lo.y = f2bf(v.y - bfval(hi.y));
        hi.z = f2bf(v.z); lo.z = f2bf(v.z - bfval(hi.z));
        hi.w = f2bf(v.w); lo.w = f2bf(v.w - bfval(hi.w));
        ((ushort4*)xh)[idx] = hi;
        ((ushort4*)xl)[idx] = lo;
    }
    if (idx < 192) {
        int g = idx >> 6, jj = idx & 63;
        const float* b = (g == 0) ? nb : ((g == 1) ? ob : eb);
        bcat[idx] = b[jj];
    }
    if (idx >= WTOT) return;
    float v;
    if (idx < 16384) {
        int n = idx >> 8, k = idx & 255;
        v = w_in[k * 64 + n];
    } else if (idx < 32768) {
        int r = idx - 16384;
        int n = r >> 6, k = r & 63;
        v = lin_w0[k * 256 + n];
    } else if (idx < 98304) {
        int r = idx - 32768;
        int n = r >> 8, k = r & 255;
        v = lin_w12[k * 256 + n];
    } else if (idx < 163840) {
        int r = idx - 98304;
        int n = r >> 8, k = r & 255;
        v = lin_w12[65536 + k * 256 + n];
    } else {
        int r = idx - 163840;
        int n = r >> 8, k = r & 255;
        int g = n >> 6, jj = n & 63;
        const float* w = (g == 0) ? nc1 : ((g == 1) ? oc1 : ec1);
        v = w[k * 64 + jj];
    }
    unsigned short hi = f2bf(v);
    whi[idx] = hi;
    wlo[idx] = f2bf(v - bfval(hi));
}

// ---------------- split-precision MFMA GEMM, B-tile staged in LDS ----------------
// Out[n, OUT] = A[n, K] @ W[K, OUT];  A pre-split hi/lo bf16 planes, W pre-repacked
// W^T hi/lo.  Block: (64*RG) rows x 64 cols, 4 waves; wave tile (16*RG)x64.
// RG=1 everywhere: 2x the waves of RG=2 -> per-wave global-load latency halved
// in exposure (R10->R11 change; R10 measured LDS-staging gain 479->443).
// B-hi always staged in LDS (+8-short row pad); B-lo in LDS when K<=128, else
// global with depth-2 prefetch. A global, depth-2 prefetch. One barrier total.
// MODE 0: bias+relu -> hi/lo planes.
// MODE 1: bf16 out + fused ATTN scores (blockIdx.y == head).
// MODE 3: fused output heads (blockIdx.y: 0=node,1=origin,2=etype).
template <int K, int OUT_CH, int MODE, int RG>
__global__ __launch_bounds__(256) void gemm_lds(
    const unsigned short* __restrict__ Ahp, const unsigned short* __restrict__ Alp,
    const unsigned short* __restrict__ Wh, const unsigned short* __restrict__ Wl,
    const float* __restrict__ bias,
    unsigned short* __restrict__ Outh, unsigned short* __restrict__ Outl,
    const float* __restrict__ a_src, const float* __restrict__ a_dst,
    float* __restrict__ s_src, float* __restrict__ s_dst,
    const float* __restrict__ w2n, const float* __restrict__ w2o,
    const float* __restrict__ w2e,
    const float* __restrict__ b2n, const float* __restrict__ b2o,
    const float* __restrict__ b2e,
    float* __restrict__ outbuf, int nreal) {
    constexpr int LB = K + 8;                 // shorts per padded LDS row
    constexpr bool LO_LDS = (K <= 128);       // both planes fit?
    __shared__ unsigned short Bh[64 * LB];
    __shared__ unsigned short Bl[LO_LDS ? 64 * LB : 64];
    const int tid = threadIdx.x;
    const int wv = tid >> 6, lane = tid & 63;
    const int quad = lane >> 4, ln = lane & 15;
    const int mb = blockIdx.x * (64 * RG);
    const int cb = blockIdx.y * 64;
    const int r0 = mb + wv * (16 * RG) + ln;

    // stage B tile into LDS (rows cb..cb+63, k-contig, padded rows)
    constexpr int NCHK = 64 * (K / 8);
#pragma unroll
    for (int i = 0; i < NCHK / 256; i++) {
        int flat = tid + i * 256;
        int r = flat / (K / 8);
        int c = (flat % (K / 8)) * 8;
        *(uint4*)&Bh[r * LB + c] = *(const uint4*)&Wh[(size_t)(cb + r) * K + c];
        if (LO_LDS)
            *(uint4*)&Bl[r * LB + c] = *(const uint4*)&Wl[(size_t)(cb + r) * K + c];
    }
    __syncthreads();

    const unsigned short* aph[RG];
    const unsigned short* apl[RG];
#pragma unroll
    for (int g = 0; g < RG; g++) {
        aph[g] = Ahp + (size_t)(r0 + g * 16) * K + quad * 8;
        apl[g] = Alp + (size_t)(r0 + g * 16) * K + quad * 8;
    }
    const unsigned short* blp = Wl + (size_t)(cb + ln) * K + quad * 8;

    f32x4 acc[RG][4];
#pragma unroll
    for (int g = 0; g < RG; g++)
#pragma unroll
        for (int j = 0; j < 4; j++) {
            acc[g][j][0] = 0.f; acc[g][j][1] = 0.f;
            acc[g][j][2] = 0.f; acc[g][j][3] = 0.f;
        }

    bf16x8 ah[RG], al[RG], blg[4];
#pragma unroll
    for (int g = 0; g < RG; g++) { ah[g] = *(const bf16x8*)aph[g]; al[g] = *(const bf16x8*)apl[g]; }
    if (!LO_LDS) {
#pragma unroll
        for (int cg = 0; cg < 4; cg++) blg[cg] = *(const bf16x8*)(blp + (size_t)cg * 16 * K);
    }

#pragma unroll
    for (int kc = 0; kc < K; kc += 32) {
        bf16x8 nah[RG], nal[RG], nbl[4];
        const int kn = kc + 32;
        if (kn < K) {
#pragma unroll
            for (int g = 0; g < RG; g++) {
                nah[g] = *(const bf16x8*)(aph[g] + kn);
                nal[g] = *(const bf16x8*)(apl[g] + kn);
            }
            if (!LO_LDS) {
#pragma unroll
                for (int cg = 0; cg < 4; cg++)
                    nbl[cg] = *(const bf16x8*)(blp + (size_t)cg * 16 * K + kn);
            }
        }
#pragma unroll
        for (int cg = 0; cg < 4; cg++) {
            bf16x8 bh = *(const bf16x8*)&Bh[(cg * 16 + ln) * LB + quad * 8 + kc];
            bf16x8 bl = LO_LDS ? *(const bf16x8*)&Bl[(cg * 16 + ln) * LB + quad * 8 + kc]
                               : blg[cg];
#pragma unroll
            for (int g = 0; g < RG; g++) {
                acc[g][cg] = __builtin_amdgcn_mfma_f32_16x16x32_bf16(ah[g], bh, acc[g][cg], 0, 0, 0);
                acc[g][cg] = __builtin_amdgcn_mfma_f32_16x16x32_bf16(al[g], bh, acc[g][cg], 0, 0, 0);
                acc[g][cg] = __builtin_amdgcn_mfma_f32_16x16x32_bf16(ah[g], bl, acc[g][cg], 0, 0, 0);
            }
        }
        if (kn < K) {
#pragma unroll
            for (int g = 0; g < RG; g++) { ah[g] = nah[g]; al[g] = nal[g]; }
            if (!LO_LDS) {
#pragma unroll
                for (int cg = 0; cg < 4; cg++) blg[cg] = nbl[cg];
            }
        }
    }

    if (MODE == 1) {
        float av[4], dv[4];
#pragma unroll
        for (int cg = 0; cg < 4; cg++) {
            av[cg] = a_src[cb + cg * 16 + ln];
            dv[cg] = a_dst[cb + cg * 16 + ln];
        }
#pragma unroll
        for (int g = 0; g < RG; g++)
#pragma unroll
            for (int reg = 0; reg < 4; reg++) {
                float ps = 0.f, pd = 0.f;
#pragma unroll
                for (int cg = 0; cg < 4; cg++) {
                    float t = acc[g][cg][reg];
                    ps += t * av[cg];
                    pd += t * dv[cg];
                }
#pragma unroll
                for (int d = 1; d < 16; d <<= 1) {
                    ps += __shfl_xor(ps, d, 64);
                    pd += __shfl_xor(pd, d, 64);
                }
                if (ln == 0) {
                    int row = mb + wv * (16 * RG) + g * 16 + quad * 4 + reg;
                    if (row < nreal) {
                        s_src[row * 4 + blockIdx.y] = ps;
                        s_dst[row * 4 + blockIdx.y] = pd;
                    }
                }
            }
    }

    if (MODE == 3) {
        float bv[4];
#pragma unroll
        for (int cg = 0; cg < 4; cg++) bv[cg] = bias[cb + cg * 16 + ln];
        if (blockIdx.y < 2) {
            const float* w2 = (blockIdx.y == 0) ? w2n : w2o;
            float b2 = (blockIdx.y == 0) ? b2n[0] : b2o[0];
            float wv2[4];
#pragma unroll
            for (int cg = 0; cg < 4; cg++) wv2[cg] = w2[cg * 16 + ln];
#pragma unroll
            for (int g = 0; g < RG; g++)
#pragma unroll
                for (int reg = 0; reg < 4; reg++) {
                    float t = 0.f;
#pragma unroll
                    for (int cg = 0; cg < 4; cg++) {
                        float tv = fmaxf(acc[g][cg][reg] + bv[cg], 0.f);
                        t += tv * wv2[cg];
                    }
#pragma unroll
                    for (int d = 1; d < 16; d <<= 1) t += __shfl_xor(t, d, 64);
                    int row = mb + wv * (16 * RG) + g * 16 + quad * 4 + reg;
                    if (ln == 0 && row < nreal)
                        outbuf[blockIdx.y * NN + row] = sigmoidf_(t + b2);
                }
        } else {
            float4 w4[4];
#pragma unroll
            for (int cg = 0; cg < 4; cg++) w4[cg] = ((const float4*)w2e)[cg * 16 + ln];
#pragma unroll
            for (int g = 0; g < RG; g++)
#pragma unroll
                for (int reg = 0; reg < 4; reg++) {
                    float e0 = 0.f, e1 = 0.f, e2 = 0.f, e3 = 0.f;
#pragma unroll
                    for (int cg = 0; cg < 4; cg++) {
                        float tv = fmaxf(acc[g][cg][reg] + bv[cg], 0.f);
                        e0 += tv * w4[cg].x; e1 += tv * w4[cg].y;
                        e2 += tv * w4[cg].z; e3 += tv * w4[cg].w;
                    }
#pragma unroll
                    for (int d = 1; d < 16; d <<= 1) {
                        e0 += __shfl_xor(e0, d, 64); e1 += __shfl_xor(e1, d, 64);
                        e2 += __shfl_xor(e2, d, 64); e3 += __shfl_xor(e3, d, 64);
                    }
                    int row = mb + wv * (16 * RG) + g * 16 + quad * 4 + reg;
                    if (ln == 0 && row < nreal) {
                        float4 ev = make_float4(e0 + b2e[0], e1 + b2e[1], e2 + b2e[2], e3 + b2e[3]);
                        *(float4*)&outbuf[2 * NN + row * 4] = ev;
                    }
                }
        }
        return;
    }

    // D layout: row = quad*4 + reg, col = ln (within each 16x16 tile)
#pragma unroll
    for (int g = 0; g < RG; g++)
#pragma unroll
        for (int cg = 0; cg < 4; cg++) {
            int col = cb + cg * 16 + ln;
            int rbase = mb + wv * (16 * RG) + g * 16 + quad * 4;
#pragma unroll
            for (int reg = 0; reg < 4; reg++) {
                float v = acc[g][cg][reg];
                int r = rbase + reg;
                if (MODE == 0) {
                    v += bias[col]; v = fmaxf(v, 0.f);
                    unsigned short hi = f2bf(v);
                    Outh[(size_t)r * OUT_CH + col] = hi;
                    Outl[(size_t)r * OUT_CH + col] = f2bf(v - bfval(hi));
                } else if (MODE == 1) {
                    Outh[(size_t)r * OUT_CH + col] = f2bf(v);
                }
            }
        }
}

// ---------------- per-dst-node GAT aggregation: single fused pass ----------------
// R7 structure + software prefetch: the next chunk's csr[] -> s_src[] dependent
// chain (~400 cyc) is issued before the current chunk's 16-gather batch so it
// overlaps instead of serializing.
__global__ __launch_bounds__(256) void gat_node(const unsigned short* __restrict__ hhb,
                                                const float* __restrict__ s_src,
                                                const float* __restrict__ s_dst,
                                                const int* __restrict__ csr_src,
                                                const int* __restrict__ csr_off,
                                                const float* __restrict__ gbias,
                                                const float* __restrict__ conf_w,
                                                const float* __restrict__ conf_b,
                                                const float* __restrict__ confid,
                                                unsigned short* __restrict__ h_hi,
                                                unsigned short* __restrict__ h_lo,
                                                float* __restrict__ outbuf,
                                                int layer) {
    __shared__ float Lc[4][64];
    __shared__ int   Ls[4][16];
    int wv = threadIdx.x >> 6;
    int lane = threadIdx.x & 63;
    int n = blockIdx.x * 4 + wv;
    int myhead = lane >> 4, slot = lane & 15;
    int off0 = csr_off[n];
    int deg = csr_off[n + 1] - off0;     // deg >= 1 (self loop)
    const int* cp = csr_src + off0;
    const unsigned short* hrow = hhb + lane * 4;
    float sdm = s_dst[n * 4 + myhead];

    float ax = 0.f, ay = 0.f, az = 0.f, aw = 0.f, smp = 0.f;
    int nch = (deg + 15) >> 4;
    // preload chunk 0 coef inputs
    bool valid = slot < deg;
    int sl = cp[valid ? slot : deg - 1];
    float ssv = s_src[sl * 4 + myhead];
    for (int t = 0; t < nch; t++) {
        float a = ssv + sdm;
        a = a > 0.f ? a : NEG * a;
        float c = valid ? __expf(a) : 0.f;
        smp += c;
        Lc[wv][lane] = c;
        if (myhead == 0) Ls[wv][slot] = sl;
        __builtin_amdgcn_wave_barrier();
        float4 c0 = *(const float4*)&Lc[wv][myhead * 16 + 0];
        float4 c1 = *(const float4*)&Lc[wv][myhead * 16 + 4];
        float4 c2 = *(const float4*)&Lc[wv][myhead * 16 + 8];
        float4 c3 = *(const float4*)&Lc[wv][myhead * 16 + 12];
        int4 s0 = *(const int4*)&Ls[wv][0];
        int4 s1 = *(const int4*)&Ls[wv][4];
        int4 s2 = *(const int4*)&Ls[wv][8];
        int4 s3 = *(const int4*)&Ls[wv][12];
        __builtin_amdgcn_wave_barrier();
        // prefetch next chunk's coef inputs (overlaps with the gather batch)
        if (t + 1 < nch) {
            int i = ((t + 1) << 4) + slot;
            valid = i < deg;
            sl = cp[valid ? i : deg - 1];
            ssv = s_src[sl * 4 + myhead];
        }
        float cf[16] = {c0.x, c0.y, c0.z, c0.w, c1.x, c1.y, c1.z, c1.w,
                        c2.x, c2.y, c2.z, c2.w, c3.x, c3.y, c3.z, c3.w};
        int sv[16] = {s0.x, s0.y, s0.z, s0.w, s1.x, s1.y, s1.z, s1.w,
                      s2.x, s2.y, s2.z, s2.w, s3.x, s3.y, s3.z, s3.w};
#pragma unroll
        for (int q = 0; q < 16; q++) {
            uint2 u = *(const uint2*)(hrow + ((size_t)sv[q] << 8));
            ax += cf[q] * bf_lo(u.x); ay += cf[q] * bf_hi(u.x);
            az += cf[q] * bf_lo(u.y); aw += cf[q] * bf_hi(u.y);
        }
    }
    smp += __shfl_xor(smp, 1, 64);
    smp += __shfl_xor(smp, 2, 64);
    smp += __shfl_xor(smp, 4, 64);
    smp += __shfl_xor(smp, 8, 64);
    float inv = 1.0f / fmaxf(smp, 1e-16f);
    ax *= inv; ay *= inv; az *= inv; aw *= inv;

    float4 b4 = *(const float4*)&gbias[lane * 4];
    float hx = ax + b4.x, hy = ay + b4.y, hz = az + b4.z, hw = aw + b4.w;
    float4 cw4 = *(const float4*)&conf_w[lane * 4];
    float local = hx * cw4.x + hy * cw4.y + hz * cw4.z + hw * cw4.w;
    float tot = wred_sum(local);
    float cw = sigmoidf_(tot + conf_b[0]) * sigmoidf_(confid[n]);
    hx *= cw; hy *= cw; hz *= cw; hw *= cw;
    if (layer > 0) {
        ushort4 ph = *(const ushort4*)&h_hi[(size_t)n * HC + lane * 4];
        ushort4 pl = *(const ushort4*)&h_lo[(size_t)n * HC + lane * 4];
        hx += bfval(ph.x) + bfval(pl.x);
        hy += bfval(ph.y) + bfval(pl.y);
        hz += bfval(ph.z) + bfval(pl.z);
        hw += bfval(ph.w) + bfval(pl.w);
    }
    if (layer < 2) {
        hx = fmaxf(hx, 0.f); hy = fmaxf(hy, 0.f);
        hz = fmaxf(hz, 0.f); hw = fmaxf(hw, 0.f);
    } else {
        *(float4*)&outbuf[6 * NN + (size_t)n * HC + lane * 4] =
            make_float4(hx, hy, hz, hw);
    }
    ushort4 oh, ol;
    oh.x = f2bf(hx); ol.x = f2bf(hx - bfval(oh.x));
    oh.y = f2bf(hy); ol.y = f2bf(hy - bfval(oh.y));
    oh.z = f2bf(hz); ol.z = f2bf(hz - bfval(oh.z));
    oh.w = f2bf(hw); ol.w = f2bf(hw - bfval(oh.w));
    *(ushort4*)&h_hi[(size_t)n * HC + lane * 4] = oh;
    *(ushort4*)&h_lo[(size_t)n * HC + lane * 4] = ol;
}

extern "C" void kernel_launch(void* const* d_in, const int* in_sizes, int n_in,
                              void* d_out, int out_size, void* d_ws, size_t ws_size,
                              hipStream_t stream) {
    const float* x       = (const float*)d_in[0];
    const int*   ei      = (const int*)d_in[1];
    const float* conf    = (const float*)d_in[2];
    const float* w_in    = (const float*)d_in[3];
    const float* b_in    = (const float*)d_in[4];
    const float* lin_w0  = (const float*)d_in[5];
    const float* lin_w12 = (const float*)d_in[6];
    const float* att_src = (const float*)d_in[7];
    const float* att_dst = (const float*)d_in[8];
    const float* gbias   = (const float*)d_in[9];
    const float* conf_w  = (const float*)d_in[10];
    const float* conf_b  = (const float*)d_in[11];
    const float* nc_w1   = (const float*)d_in[12];
    const float* nc_b1   = (const float*)d_in[13];
    const float* nc_w2   = (const float*)d_in[14];
    const float* nc_b2   = (const float*)d_in[15];
    const float* oc_w1   = (const float*)d_in[16];
    const float* oc_b1   = (const float*)d_in[17];
    const float* oc_w2   = (const float*)d_in[18];
    const float* oc_b2   = (const float*)d_in[19];
    const float* ec_w1   = (const float*)d_in[20];
    const float* ec_b1   = (const float*)d_in[21];
    const float* ec_w2   = (const float*)d_in[22];
    const float* ec_b2   = (const float*)d_in[23];
    float* out = (float*)d_out;

    char* p = (char*)d_ws;
    auto alloc = [&](size_t bytes) -> void* {
        void* r = (void*)p;
        p += (bytes + 255) & ~(size_t)255;
        return r;
    };
    unsigned short* h_hi = (unsigned short*)alloc((size_t)NPAD * HC * 2);
    unsigned short* h_lo = (unsigned short*)alloc((size_t)NPAD * HC * 2);
    unsigned short* hh   = (unsigned short*)alloc((size_t)NPAD * HC * 2);
    unsigned short* h0h  = (unsigned short*)alloc((size_t)NPAD * CC * 2);
    unsigned short* h0l  = (unsigned short*)alloc((size_t)NPAD * CC * 2);
    float*          ssrc = (float*)alloc((size_t)NN * 4 * 4);
    float*          sdst = (float*)alloc((size_t)NN * 4 * 4);
    int*            cnt  = (int*)alloc((size_t)NN * 4);
    int*            off  = (int*)alloc((size_t)(NN + 1) * 4);
    int*            cur  = (int*)alloc((size_t)NN * 4);
    int*            csr  = (int*)alloc((size_t)E2 * 4);
    unsigned short* whi  = (unsigned short*)alloc((size_t)WTOT * 2);
    unsigned short* wlo  = (unsigned short*)alloc((size_t)WTOT * 2);
    float*          bcat = (float*)alloc((size_t)192 * 4);
    unsigned short* xh   = (unsigned short*)alloc((size_t)NPAD * 256 * 2 * 2);
    unsigned short* xl   = xh + (size_t)NPAD * 256;

    const unsigned short* wt_in = whi;            const unsigned short* wt_in_l = wlo;
    const unsigned short* wt_l0 = whi + 16384;    const unsigned short* wt_l0_l = wlo + 16384;
    const unsigned short* wt_a  = whi + 32768;    const unsigned short* wt_a_l  = wlo + 32768;
    const unsigned short* wt_b  = whi + 98304;    const unsigned short* wt_b_l  = wlo + 98304;
    const unsigned short* wt_hd = whi + 163840;   const unsigned short* wt_hd_l = wlo + 163840;

    // CSR by dst (with self loops appended)
    hipMemsetAsync(cnt, 0, (size_t)NN * 4, stream);
    count_edges<<<(E2 + 255) / 256, 256, 0, stream>>>(ei, cnt);
    scan_off<<<1, 1024, 0, stream>>>(cnt, off, cur);
    scatter_edges<<<(E2 + 255) / 256, 256, 0, stream>>>(ei, cur, csr);

    // fused prep: weight repack + x split + bcat
    prep_inputs<<<(NN * 64 + 255) / 256, 256, 0, stream>>>(
        x, w_in, lin_w0, lin_w12, nc_w1, oc_w1, ec_w1, nc_b1, oc_b1, ec_b1,
        whi, wlo, bcat, xh, xl);

    // input projection + relu -> h0 hi/lo planes
    gemm_lds<256, 64, 0, 1><<<dim3(NPAD / 64, 1), 256, 0, stream>>>(
        xh, xl, wt_in, wt_in_l, b_in, h0h, h0l, nullptr, nullptr, nullptr, nullptr,
        nullptr, nullptr, nullptr, nullptr, nullptr, nullptr, nullptr, NN);

    // GAT layer 0 (in=64): hh (bf16) + fused attention scores
    gemm_lds<64, 256, 1, 1><<<dim3(NPAD / 64, 4), 256, 0, stream>>>(
        h0h, h0l, wt_l0, wt_l0_l, nullptr, hh, nullptr, att_src, att_dst, ssrc, sdst,
        nullptr, nullptr, nullptr, nullptr, nullptr, nullptr, nullptr, NN);
    gat_node<<<NN / 4, 256, 0, stream>>>(hh, ssrc, sdst, csr, off, gbias, conf_w, conf_b, conf,
                                         h_hi, h_lo, out, 0);

    // GAT layers 1,2 (in=256)
    for (int i = 1; i < 3; i++) {
        const unsigned short* wh = (i == 1) ? wt_a : wt_b;
        const unsigned short* wl = (i == 1) ? wt_a_l : wt_b_l;
        gemm_lds<256, 256, 1, 1><<<dim3(NPAD / 64, 4), 256, 0, stream>>>(
            h_hi, h_lo, wh, wl, nullptr, hh, nullptr,
            att_src + i * HHD * CC, att_dst + i * HHD * CC, ssrc, sdst,
            nullptr, nullptr, nullptr, nullptr, nullptr, nullptr, nullptr, NN);
        gat_node<<<NN / 4, 256, 0, stream>>>(hh, ssrc, sdst, csr, off, gbias + i * HC,
                                             conf_w, conf_b, conf, h_hi, h_lo, out, i);
    }

    // fused heads: one dispatch computes node/origin/etype outputs directly
    gemm_lds<256, 192, 3, 1><<<dim3(NPAD / 64, 3), 256, 0, stream>>>(
        h_hi, h_lo, wt_hd, wt_hd_l, bcat, nullptr, nullptr, nullptr, nullptr, nullptr, nullptr,
        nc_w2, oc_w2, ec_w2, nc_b2, oc_b2, ec_b2, out, NN);
}

// Round 12
// 421.502 us; speedup vs baseline: 1.0832x; 1.0832x over previous
//
#include <hip/hip_runtime.h>
#include <cstdint>
#include <cstddef>

#define NN   20000
#define NPAD 20224   // 316*64
#define EE   640000
#define E2   660000   // EE + NN self loops
#define HHD  4
#define CC   64
#define HC   256
#define NEG  0.2f

typedef short bf16x8 __attribute__((ext_vector_type(8)));
typedef float f32x4 __attribute__((ext_vector_type(4)));

__device__ __forceinline__ float sigmoidf_(float x) { return 1.0f / (1.0f + __expf(-x)); }

__device__ __forceinline__ float wred_sum(float v) {
#pragma unroll
    for (int d = 32; d; d >>= 1) v += __shfl_xor(v, d, 64);
    return v;
}

__device__ __forceinline__ unsigned short f2bf(float f) {
    unsigned u = __float_as_uint(f);
    u = (u + 0x7fff + ((u >> 16) & 1)) >> 16;   // RNE
    return (unsigned short)u;
}
__device__ __forceinline__ float bfval(unsigned short h) { return __uint_as_float(((unsigned)h) << 16); }
__device__ __forceinline__ float bf_lo(unsigned u) { return __uint_as_float(u << 16); }
__device__ __forceinline__ float bf_hi(unsigned u) { return __uint_as_float(u & 0xffff0000u); }

// ---------------- CSR build ----------------
__global__ void count_edges(const int* __restrict__ ei, int* __restrict__ cnt) {
    int e = blockIdx.x * 256 + threadIdx.x;
    if (e < E2) {
        int d = (e < EE) ? ei[EE + e] : (e - EE);
        atomicAdd(&cnt[d], 1);
    }
}

__global__ __launch_bounds__(1024) void scan_off(const int* __restrict__ cnt,
                                                 int* __restrict__ off,
                                                 int* __restrict__ cur) {
    __shared__ int buf[1024];
    int t = threadIdx.x;
    int base = t * 20;
    int local[20];
    int s = 0;
#pragma unroll
    for (int i = 0; i < 20; i++) {
        int idx = base + i;
        int v = (idx < NN) ? cnt[idx] : 0;
        local[i] = v;
        s += v;
    }
    buf[t] = s;
    __syncthreads();
    for (int d = 1; d < 1024; d <<= 1) {
        int tv = (t >= d) ? buf[t - d] : 0;
        __syncthreads();
        buf[t] += tv;
        __syncthreads();
    }
    int run = buf[t] - s;
#pragma unroll
    for (int i = 0; i < 20; i++) {
        int idx = base + i;
        if (idx < NN) { off[idx] = run; cur[idx] = run; }
        run += local[i];
    }
    if (t == 1023) off[NN] = buf[1023];
}

__global__ void scatter_edges(const int* __restrict__ ei, int* __restrict__ cur,
                              int* __restrict__ csr) {
    int e = blockIdx.x * 256 + threadIdx.x;
    if (e < E2) {
        int s, d;
        if (e < EE) { s = ei[e]; d = ei[EE + e]; }
        else        { s = e - EE; d = s; }
        int p = atomicAdd(&cur[d], 1);
        csr[p] = s;
    }
}

// ---------------- fused prep: weight repack (hi-only W^T bf16) + x split + bcat ----------------
#define WTOT 212992
__global__ void prep_inputs(const float* __restrict__ x,
                            const float* __restrict__ w_in, const float* __restrict__ lin_w0,
                            const float* __restrict__ lin_w12,
                            const float* __restrict__ nc1, const float* __restrict__ oc1,
                            const float* __restrict__ ec1,
                            const float* __restrict__ nb, const float* __restrict__ ob,
                            const float* __restrict__ eb,
                            unsigned short* __restrict__ whi,
                            float* __restrict__ bcat,
                            unsigned short* __restrict__ xh, unsigned short* __restrict__ xl) {
    int idx = blockIdx.x * 256 + threadIdx.x;
    if (idx < NN * 64) {
        float4 v = ((const float4*)x)[idx];
        ushort4 hi, lo;
        hi.x = f2bf(v.x); lo.x = f2bf(v.x - bfval(hi.x));
        hi.y = f2bf(v.y); lo.y = f2bf(v.y - bfval(hi.y));
        hi.z = f2bf(v.z); lo.z = f2bf(v.z - bfval(hi.z));
        hi.w = f2bf(v.w); lo.w = f2bf(v.w - bfval(hi.w));
        ((ushort4*)xh)[idx] = hi;
        ((ushort4*)xl)[idx] = lo;
    }
    if (idx < 192) {
        int g = idx >> 6, jj = idx & 63;
        const float* b = (g == 0) ? nb : ((g == 1) ? ob : eb);
        bcat[idx] = b[jj];
    }
    if (idx >= WTOT) return;
    float v;
    if (idx < 16384) {
        int n = idx >> 8, k = idx & 255;
        v = w_in[k * 64 + n];
    } else if (idx < 32768) {
        int r = idx - 16384;
        int n = r >> 6, k = r & 63;
        v = lin_w0[k * 256 + n];
    } else if (idx < 98304) {
        int r = idx - 32768;
        int n = r >> 8, k = r & 255;
        v = lin_w12[k * 256 + n];
    } else if (idx < 163840) {
        int r = idx - 98304;
        int n = r >> 8, k = r & 255;
        v = lin_w12[65536 + k * 256 + n];
    } else {
        int r = idx - 163840;
        int n = r >> 8, k = r & 255;
        int g = n >> 6, jj = n & 63;
        const float* w = (g == 0) ? nc1 : ((g == 1) ? oc1 : ec1);
        v = w[k * 64 + jj];
    }
    whi[idx] = f2bf(v);
}

// ---------------- 2-term split MFMA GEMM: full-K A prefetch + LDS B ----------------
// Out[n, OUT] = A[n, K] @ W[K, OUT];  A = hi/lo bf16 planes (A precision kept via
// al*bh term), W = bf16 (hi only; weight-rounding error ~2^-9 rel, absmax-safe).
// Block: 64 rows x 64 cols, 4 waves, wave tile 16x64.
// ALL K/32 x2 A-fragment loads issued up-front (16 outstanding vmem per wave,
// latency overlaps B staging + barrier); K-loop is LDS reads + MFMA only.
// MODE 0: bias+relu -> hi/lo planes.
// MODE 1: bf16 out + fused ATTN scores (blockIdx.y == head).
// MODE 3: fused output heads (blockIdx.y: 0=node,1=origin,2=etype).
template <int K, int OUT_CH, int MODE>
__global__ __launch_bounds__(256) void gemm_lds(
    const unsigned short* __restrict__ Ahp, const unsigned short* __restrict__ Alp,
    const unsigned short* __restrict__ Wh,
    const float* __restrict__ bias,
    unsigned short* __restrict__ Outh, unsigned short* __restrict__ Outl,
    const float* __restrict__ a_src, const float* __restrict__ a_dst,
    float* __restrict__ s_src, float* __restrict__ s_dst,
    const float* __restrict__ w2n, const float* __restrict__ w2o,
    const float* __restrict__ w2e,
    const float* __restrict__ b2n, const float* __restrict__ b2o,
    const float* __restrict__ b2e,
    float* __restrict__ outbuf, int nreal) {
    constexpr int LB = K + 8;                 // shorts per padded LDS row
    constexpr int NS = K / 32;                // k-steps
    __shared__ unsigned short Bh[64 * LB];
    const int tid = threadIdx.x;
    const int wv = tid >> 6, lane = tid & 63;
    const int quad = lane >> 4, ln = lane & 15;
    const int mb = blockIdx.x * 64;
    const int cb = blockIdx.y * 64;
    const int r0 = mb + wv * 16 + ln;

    // 1) issue ALL A-fragment loads first (deep MLP; overlaps staging+barrier)
    const unsigned short* aph = Ahp + (size_t)r0 * K + quad * 8;
    const unsigned short* apl = Alp + (size_t)r0 * K + quad * 8;
    bf16x8 ah[NS], al[NS];
#pragma unroll
    for (int s = 0; s < NS; s++) {
        ah[s] = *(const bf16x8*)(aph + s * 32);
        al[s] = *(const bf16x8*)(apl + s * 32);
    }

    // 2) stage B tile into LDS (rows cb..cb+63, k-contig, padded rows)
    constexpr int NCHK = 64 * (K / 8);
#pragma unroll
    for (int i = 0; i < NCHK / 256; i++) {
        int flat = tid + i * 256;
        int r = flat / (K / 8);
        int c = (flat % (K / 8)) * 8;
        *(uint4*)&Bh[r * LB + c] = *(const uint4*)&Wh[(size_t)(cb + r) * K + c];
    }
    __syncthreads();

    f32x4 acc[4];
#pragma unroll
    for (int j = 0; j < 4; j++) {
        acc[j][0] = 0.f; acc[j][1] = 0.f; acc[j][2] = 0.f; acc[j][3] = 0.f;
    }

    // 3) K-loop: LDS B reads + MFMA only (2-term: ah*bh + al*bh)
#pragma unroll
    for (int s = 0; s < NS; s++) {
#pragma unroll
        for (int cg = 0; cg < 4; cg++) {
            bf16x8 bh = *(const bf16x8*)&Bh[(cg * 16 + ln) * LB + quad * 8 + s * 32];
            acc[cg] = __builtin_amdgcn_mfma_f32_16x16x32_bf16(ah[s], bh, acc[cg], 0, 0, 0);
            acc[cg] = __builtin_amdgcn_mfma_f32_16x16x32_bf16(al[s], bh, acc[cg], 0, 0, 0);
        }
    }

    if (MODE == 1) {
        float av[4], dv[4];
#pragma unroll
        for (int cg = 0; cg < 4; cg++) {
            av[cg] = a_src[cb + cg * 16 + ln];
            dv[cg] = a_dst[cb + cg * 16 + ln];
        }
#pragma unroll
        for (int reg = 0; reg < 4; reg++) {
            float ps = 0.f, pd = 0.f;
#pragma unroll
            for (int cg = 0; cg < 4; cg++) {
                float t = acc[cg][reg];
                ps += t * av[cg];
                pd += t * dv[cg];
            }
#pragma unroll
            for (int d = 1; d < 16; d <<= 1) {
                ps += __shfl_xor(ps, d, 64);
                pd += __shfl_xor(pd, d, 64);
            }
            if (ln == 0) {
                int row = mb + wv * 16 + quad * 4 + reg;
                if (row < nreal) {
                    s_src[row * 4 + blockIdx.y] = ps;
                    s_dst[row * 4 + blockIdx.y] = pd;
                }
            }
        }
    }

    if (MODE == 3) {
        float bv[4];
#pragma unroll
        for (int cg = 0; cg < 4; cg++) bv[cg] = bias[cb + cg * 16 + ln];
        if (blockIdx.y < 2) {
            const float* w2 = (blockIdx.y == 0) ? w2n : w2o;
            float b2 = (blockIdx.y == 0) ? b2n[0] : b2o[0];
            float wv2[4];
#pragma unroll
            for (int cg = 0; cg < 4; cg++) wv2[cg] = w2[cg * 16 + ln];
#pragma unroll
            for (int reg = 0; reg < 4; reg++) {
                float t = 0.f;
#pragma unroll
                for (int cg = 0; cg < 4; cg++) {
                    float tv = fmaxf(acc[cg][reg] + bv[cg], 0.f);
                    t += tv * wv2[cg];
                }
#pragma unroll
                for (int d = 1; d < 16; d <<= 1) t += __shfl_xor(t, d, 64);
                int row = mb + wv * 16 + quad * 4 + reg;
                if (ln == 0 && row < nreal)
                    outbuf[blockIdx.y * NN + row] = sigmoidf_(t + b2);
            }
        } else {
            float4 w4[4];
#pragma unroll
            for (int cg = 0; cg < 4; cg++) w4[cg] = ((const float4*)w2e)[cg * 16 + ln];
#pragma unroll
            for (int reg = 0; reg < 4; reg++) {
                float e0 = 0.f, e1 = 0.f, e2 = 0.f, e3 = 0.f;
#pragma unroll
                for (int cg = 0; cg < 4; cg++) {
                    float tv = fmaxf(acc[cg][reg] + bv[cg], 0.f);
                    e0 += tv * w4[cg].x; e1 += tv * w4[cg].y;
                    e2 += tv * w4[cg].z; e3 += tv * w4[cg].w;
                }
#pragma unroll
                for (int d = 1; d < 16; d <<= 1) {
                    e0 += __shfl_xor(e0, d, 64); e1 += __shfl_xor(e1, d, 64);
                    e2 += __shfl_xor(e2, d, 64); e3 += __shfl_xor(e3, d, 64);
                }
                int row = mb + wv * 16 + quad * 4 + reg;
                if (ln == 0 && row < nreal) {
                    float4 ev = make_float4(e0 + b2e[0], e1 + b2e[1], e2 + b2e[2], e3 + b2e[3]);
                    *(float4*)&outbuf[2 * NN + row * 4] = ev;
                }
            }
        }
        return;
    }

    // D layout: row = quad*4 + reg, col = ln (within each 16x16 tile)
#pragma unroll
    for (int cg = 0; cg < 4; cg++) {
        int col = cb + cg * 16 + ln;
        int rbase = mb + wv * 16 + quad * 4;
#pragma unroll
        for (int reg = 0; reg < 4; reg++) {
            float v = acc[cg][reg];
            int r = rbase + reg;
            if (MODE == 0) {
                v += bias[col]; v = fmaxf(v, 0.f);
                unsigned short hi = f2bf(v);
                Outh[(size_t)r * OUT_CH + col] = hi;
                Outl[(size_t)r * OUT_CH + col] = f2bf(v - bfval(hi));
            } else if (MODE == 1) {
                Outh[(size_t)r * OUT_CH + col] = f2bf(v);
            }
        }
    }
}

// ---------------- per-dst-node GAT aggregation (R11 form, proven) ----------------
__global__ __launch_bounds__(256) void gat_node(const unsigned short* __restrict__ hhb,
                                                const float* __restrict__ s_src,
                                                const float* __restrict__ s_dst,
                                                const int* __restrict__ csr_src,
                                                const int* __restrict__ csr_off,
                                                const float* __restrict__ gbias,
                                                const float* __restrict__ conf_w,
                                                const float* __restrict__ conf_b,
                                                const float* __restrict__ confid,
                                                unsigned short* __restrict__ h_hi,
                                                unsigned short* __restrict__ h_lo,
                                                float* __restrict__ outbuf,
                                                int layer) {
    __shared__ float Lc[4][64];
    __shared__ int   Ls[4][16];
    int wv = threadIdx.x >> 6;
    int lane = threadIdx.x & 63;
    int n = blockIdx.x * 4 + wv;
    int myhead = lane >> 4, slot = lane & 15;
    int off0 = csr_off[n];
    int deg = csr_off[n + 1] - off0;     // deg >= 1 (self loop)
    const int* cp = csr_src + off0;
    const unsigned short* hrow = hhb + lane * 4;
    float sdm = s_dst[n * 4 + myhead];

    float ax = 0.f, ay = 0.f, az = 0.f, aw = 0.f, smp = 0.f;
    int nch = (deg + 15) >> 4;
    bool valid = slot < deg;
    int sl = cp[valid ? slot : deg - 1];
    float ssv = s_src[sl * 4 + myhead];
    for (int t = 0; t < nch; t++) {
        float a = ssv + sdm;
        a = a > 0.f ? a : NEG * a;
        float c = valid ? __expf(a) : 0.f;
        smp += c;
        Lc[wv][lane] = c;
        if (myhead == 0) Ls[wv][slot] = sl;
        __builtin_amdgcn_wave_barrier();
        float4 c0 = *(const float4*)&Lc[wv][myhead * 16 + 0];
        float4 c1 = *(const float4*)&Lc[wv][myhead * 16 + 4];
        float4 c2 = *(const float4*)&Lc[wv][myhead * 16 + 8];
        float4 c3 = *(const float4*)&Lc[wv][myhead * 16 + 12];
        int4 s0 = *(const int4*)&Ls[wv][0];
        int4 s1 = *(const int4*)&Ls[wv][4];
        int4 s2 = *(const int4*)&Ls[wv][8];
        int4 s3 = *(const int4*)&Ls[wv][12];
        __builtin_amdgcn_wave_barrier();
        if (t + 1 < nch) {
            int i = ((t + 1) << 4) + slot;
            valid = i < deg;
            sl = cp[valid ? i : deg - 1];
            ssv = s_src[sl * 4 + myhead];
        }
        float cf[16] = {c0.x, c0.y, c0.z, c0.w, c1.x, c1.y, c1.z, c1.w,
                        c2.x, c2.y, c2.z, c2.w, c3.x, c3.y, c3.z, c3.w};
        int sv[16] = {s0.x, s0.y, s0.z, s0.w, s1.x, s1.y, s1.z, s1.w,
                      s2.x, s2.y, s2.z, s2.w, s3.x, s3.y, s3.z, s3.w};
#pragma unroll
        for (int q = 0; q < 16; q++) {
            uint2 u = *(const uint2*)(hrow + ((size_t)sv[q] << 8));
            ax += cf[q] * bf_lo(u.x); ay += cf[q] * bf_hi(u.x);
            az += cf[q] * bf_lo(u.y); aw += cf[q] * bf_hi(u.y);
        }
    }
    smp += __shfl_xor(smp, 1, 64);
    smp += __shfl_xor(smp, 2, 64);
    smp += __shfl_xor(smp, 4, 64);
    smp += __shfl_xor(smp, 8, 64);
    float inv = 1.0f / fmaxf(smp, 1e-16f);
    ax *= inv; ay *= inv; az *= inv; aw *= inv;

    float4 b4 = *(const float4*)&gbias[lane * 4];
    float hx = ax + b4.x, hy = ay + b4.y, hz = az + b4.z, hw = aw + b4.w;
    float4 cw4 = *(const float4*)&conf_w[lane * 4];
    float local = hx * cw4.x + hy * cw4.y + hz * cw4.z + hw * cw4.w;
    float tot = wred_sum(local);
    float cw = sigmoidf_(tot + conf_b[0]) * sigmoidf_(confid[n]);
    hx *= cw; hy *= cw; hz *= cw; hw *= cw;
    if (layer > 0) {
        ushort4 ph = *(const ushort4*)&h_hi[(size_t)n * HC + lane * 4];
        ushort4 pl = *(const ushort4*)&h_lo[(size_t)n * HC + lane * 4];
        hx += bfval(ph.x) + bfval(pl.x);
        hy += bfval(ph.y) + bfval(pl.y);
        hz += bfval(ph.z) + bfval(pl.z);
        hw += bfval(ph.w) + bfval(pl.w);
    }
    if (layer < 2) {
        hx = fmaxf(hx, 0.f); hy = fmaxf(hy, 0.f);
        hz = fmaxf(hz, 0.f); hw = fmaxf(hw, 0.f);
    } else {
        *(float4*)&outbuf[6 * NN + (size_t)n * HC + lane * 4] =
            make_float4(hx, hy, hz, hw);
    }
    ushort4 oh, ol;
    oh.x = f2bf(hx); ol.x = f2bf(hx - bfval(oh.x));
    oh.y = f2bf(hy); ol.y = f2bf(hy - bfval(oh.y));
    oh.z = f2bf(hz); ol.z = f2bf(hz - bfval(oh.z));
    oh.w = f2bf(hw); ol.w = f2bf(hw - bfval(oh.w));
    *(ushort4*)&h_hi[(size_t)n * HC + lane * 4] = oh;
    *(ushort4*)&h_lo[(size_t)n * HC + lane * 4] = ol;
}

extern "C" void kernel_launch(void* const* d_in, const int* in_sizes, int n_in,
                              void* d_out, int out_size, void* d_ws, size_t ws_size,
                              hipStream_t stream) {
    const float* x       = (const float*)d_in[0];
    const int*   ei      = (const int*)d_in[1];
    const float* conf    = (const float*)d_in[2];
    const float* w_in    = (const float*)d_in[3];
    const float* b_in    = (const float*)d_in[4];
    const float* lin_w0  = (const float*)d_in[5];
    const float* lin_w12 = (const float*)d_in[6];
    const float* att_src = (const float*)d_in[7];
    const float* att_dst = (const float*)d_in[8];
    const float* gbias   = (const float*)d_in[9];
    const float* conf_w  = (const float*)d_in[10];
    const float* conf_b  = (const float*)d_in[11];
    const float* nc_w1   = (const float*)d_in[12];
    const float* nc_b1   = (const float*)d_in[13];
    const float* nc_w2   = (const float*)d_in[14];
    const float* nc_b2   = (const float*)d_in[15];
    const float* oc_w1   = (const float*)d_in[16];
    const float* oc_b1   = (const float*)d_in[17];
    const float* oc_w2   = (const float*)d_in[18];
    const float* oc_b2   = (const float*)d_in[19];
    const float* ec_w1   = (const float*)d_in[20];
    const float* ec_b1   = (const float*)d_in[21];
    const float* ec_w2   = (const float*)d_in[22];
    const float* ec_b2   = (const float*)d_in[23];
    float* out = (float*)d_out;

    char* p = (char*)d_ws;
    auto alloc = [&](size_t bytes) -> void* {
        void* r = (void*)p;
        p += (bytes + 255) & ~(size_t)255;
        return r;
    };
    unsigned short* h_hi = (unsigned short*)alloc((size_t)NPAD * HC * 2);
    unsigned short* h_lo = (unsigned short*)alloc((size_t)NPAD * HC * 2);
    unsigned short* hh   = (unsigned short*)alloc((size_t)NPAD * HC * 2);
    unsigned short* h0h  = (unsigned short*)alloc((size_t)NPAD * CC * 2);
    unsigned short* h0l  = (unsigned short*)alloc((size_t)NPAD * CC * 2);
    float*          ssrc = (float*)alloc((size_t)NN * 4 * 4);
    float*          sdst = (float*)alloc((size_t)NN * 4 * 4);
    int*            cnt  = (int*)alloc((size_t)NN * 4);
    int*            off  = (int*)alloc((size_t)(NN + 1) * 4);
    int*            cur  = (int*)alloc((size_t)NN * 4);
    int*            csr  = (int*)alloc((size_t)E2 * 4);
    unsigned short* whi  = (unsigned short*)alloc((size_t)WTOT * 2);
    float*          bcat = (float*)alloc((size_t)192 * 4);
    unsigned short* xh   = (unsigned short*)alloc((size_t)NPAD * 256 * 2 * 2);
    unsigned short* xl   = xh + (size_t)NPAD * 256;

    const unsigned short* wt_in = whi;
    const unsigned short* wt_l0 = whi + 16384;
    const unsigned short* wt_a  = whi + 32768;
    const unsigned short* wt_b  = whi + 98304;
    const unsigned short* wt_hd = whi + 163840;

    // CSR by dst (with self loops appended)
    hipMemsetAsync(cnt, 0, (size_t)NN * 4, stream);
    count_edges<<<(E2 + 255) / 256, 256, 0, stream>>>(ei, cnt);
    scan_off<<<1, 1024, 0, stream>>>(cnt, off, cur);
    scatter_edges<<<(E2 + 255) / 256, 256, 0, stream>>>(ei, cur, csr);

    // fused prep: weight repack (bf16 W^T) + x split + bcat
    prep_inputs<<<(NN * 64 + 255) / 256, 256, 0, stream>>>(
        x, w_in, lin_w0, lin_w12, nc_w1, oc_w1, ec_w1, nc_b1, oc_b1, ec_b1,
        whi, bcat, xh, xl);

    // input projection + relu -> h0 hi/lo planes
    gemm_lds<256, 64, 0><<<dim3(NPAD / 64, 1), 256, 0, stream>>>(
        xh, xl, wt_in, b_in, h0h, h0l, nullptr, nullptr, nullptr, nullptr,
        nullptr, nullptr, nullptr, nullptr, nullptr, nullptr, nullptr, NN);

    // GAT layer 0 (in=64): hh (bf16) + fused attention scores
    gemm_lds<64, 256, 1><<<dim3(NPAD / 64, 4), 256, 0, stream>>>(
        h0h, h0l, wt_l0, nullptr, hh, nullptr, att_src, att_dst, ssrc, sdst,
        nullptr, nullptr, nullptr, nullptr, nullptr, nullptr, nullptr, NN);
    gat_node<<<NN / 4, 256, 0, stream>>>(hh, ssrc, sdst, csr, off, gbias, conf_w, conf_b, conf,
                                         h_hi, h_lo, out, 0);

    // GAT layers 1,2 (in=256)
    for (int i = 1; i < 3; i++) {
        const unsigned short* wh = (i == 1) ? wt_a : wt_b;
        gemm_lds<256, 256, 1><<<dim3(NPAD / 64, 4), 256, 0, stream>>>(
            h_hi, h_lo, wh, nullptr, hh, nullptr,
            att_src + i * HHD * CC, att_dst + i * HHD * CC, ssrc, sdst,
            nullptr, nullptr, nullptr, nullptr, nullptr, nullptr, nullptr, NN);
        gat_node<<<NN / 4, 256, 0, stream>>>(hh, ssrc, sdst, csr, off, gbias + i * HC,
                                             conf_w, conf_b, conf, h_hi, h_lo, out, i);
    }

    // fused heads: one dispatch computes node/origin/etype outputs directly
    gemm_lds<256, 192, 3><<<dim3(NPAD / 64, 3), 256, 0, stream>>>(
        h_hi, h_lo, wt_hd, bcat, nullptr, nullptr, nullptr, nullptr, nullptr, nullptr,
        nc_w2, oc_w2, ec_w2, nc_b2, oc_b2, ec_b2, out, NN);
}